// Round 6
// baseline (120.376 us; speedup 1.0000x reference)
//
#include <hip/hip_runtime.h>
#include <math.h>

#define NN 256
#define XX 256
#define TT 3
#define KK 64
#define AA 193          // 3*K+1
#define EPSF 1e-9f
#define NPART 256
#define NBLK 2048       // k_fused grid

// ws layout (bytes):
// [0, 2048)            double part[256]
// [2048, 3072)         int nsel[256]
// [3072, 4096)         int ncols[256]
// [4096, 266240)       int S[256][256]      (full `order` per n)
// [266240, 331776)     int Ck[256][64]      (full `corder` per n)
// [331776, 1118208)    float mask[196608]   (gt_class value per row, 0.0/1.0)
// [1118208, 1118212)   int ticket

typedef float float4a __attribute__((ext_vector_type(4)));

__device__ __forceinline__ float4a ld4(const float* p) {
    float4a v;
    __builtin_memcpy(&v, p, 16);   // align-4 safe
    return v;
}

__global__ __launch_bounds__(256) void k_meta(const float* __restrict__ gt,
                                              int* __restrict__ nselArr,
                                              int* __restrict__ ncolsArr,
                                              int* __restrict__ S,
                                              int* __restrict__ Ck,
                                              double* __restrict__ part,
                                              float* __restrict__ mask,
                                              int* __restrict__ ticket) {
    int n = blockIdx.x;
    int tid = threadIdx.x;
    int lane = tid & 63;
    int wave = tid >> 6;

    // zero accumulators for this call (consumers launch after us on the stream)
    if (n == 0) {
        part[tid] = 0.0;
        if (tid == 0) *ticket = 0;
    }

    __shared__ int s_S[XX];
    __shared__ int s_cnt[4];
    __shared__ float s_red[256];
    __shared__ int s_nsel;

    // ---- phase 1: sel + stable partition (the `order` array) + row mask ----
    int x = tid;
    size_t rb = ((size_t)(n * XX + x) * TT) * AA;
    float gc0 = gt[rb + 3 * KK];
    float gc1 = gt[rb + AA + 3 * KK];
    float gc2 = gt[rb + 2 * AA + 3 * KK];
    int rowid = (n * XX + x) * TT;
    mask[rowid + 0] = gc0;
    mask[rowid + 1] = gc1;
    mask[rowid + 2] = gc2;

    bool selx = gc0 > 0.0f;
    unsigned long long bal = __ballot(selx);
    if (lane == 0) s_cnt[wave] = __popcll(bal);
    __syncthreads();
    int c0 = s_cnt[0], c1 = s_cnt[1], c2 = s_cnt[2], c3 = s_cnt[3];
    int nsel_n = c0 + c1 + c2 + c3;
    int selbase = (wave > 0 ? c0 : 0) + (wave > 1 ? c1 : 0) + (wave > 2 ? c2 : 0);
    unsigned long long ltmask = (1ull << lane) - 1ull;
    int pos;
    if (selx) pos = selbase + __popcll(bal & ltmask);
    else      pos = nsel_n + (64 * wave - selbase) + __popcll((~bal) & ltmask);
    s_S[pos] = x;
    if (tid == 0) { s_nsel = nsel_n; nselArr[n] = nsel_n; }
    __syncthreads();
    S[n * XX + tid] = s_S[tid];

    // ---- phase 2: column sums over selected rows ----
    int nsl = s_nsel;
    float partial = 0.0f;
    for (int i = wave; i < nsl; i += 4) {
        int xs = s_S[i];
        size_t base = ((size_t)(n * XX + xs) * TT) * AA + 2 * KK + lane;
        partial += gt[base] + gt[base + AA] + gt[base + 2 * AA];
    }
    s_red[tid] = partial;
    __syncthreads();

    // ---- phase 3: keep + stable column partition (the `corder` array) ----
    if (tid < KK) {
        float tot = s_red[tid] + s_red[tid + 64] + s_red[tid + 128] + s_red[tid + 192];
        int nrows = nsl * TT;
        bool keep = (tot >= (float)nrows) || (tid < 5);
        unsigned long long kb = __ballot(keep);
        int nc = __popcll(kb);
        unsigned long long lt = (1ull << tid) - 1ull;
        int cpos = keep ? __popcll(kb & lt) : nc + __popcll((~kb) & lt);
        Ck[n * KK + cpos] = tid;
        if (tid == 0) ncolsArr[n] = nc;
    }
}

// Fused: (A) pairs phase (loss3/loss4 gathers, latency-bound, imbalanced),
//        (B) streaming phase (loss0/1/2, BW-bound, uniform),
//        (C) block reduce + part[] atomicAdd + last-block final sum.
// Phases A and B both accumulate into registers -> no intra-kernel sync needed.
__global__ __launch_bounds__(256) void k_fused(const float* __restrict__ pred,
                                               const float* __restrict__ gt,
                                               const float* __restrict__ mask,
                                               const float* __restrict__ hcam_arr,
                                               const float* __restrict__ ax,
                                               const float* __restrict__ ay,
                                               const float* __restrict__ xstd,
                                               const float* __restrict__ zstd,
                                               const int* __restrict__ nselArr,
                                               const int* __restrict__ ncolsArr,
                                               const int* __restrict__ S,
                                               const int* __restrict__ Ck,
                                               double* __restrict__ part,
                                               int* __restrict__ ticket,
                                               float* __restrict__ out) {
    int tid = threadIdx.x;
    int lane = tid & 63;
    int wid = tid >> 6;

    // ---- phase A: pairs (loss3 + loss4), 8 blocks per n, 32 waves per n ----
    float accp = 0.0f;
    {
        int n = blockIdx.x >> 3;
        int waveIdx = ((blockIdx.x & 7) << 2) | wid;   // 0..31
        int nrows = nselArr[n] * TT;
        int ncols = ncolsArr[n];
        int k = Ck[n * KK + lane];
        float inv_h = 1.0f / hcam_arr[n];
        float zs = zstd[k], xs = xstd[k], ayk = ay[k];
        float xstd0 = xstd[0];

        for (int i = 0; i < 24; ++i) {
            int p = i * 32 + waveIdx;                  // covers 0..767
            if (p + 1 >= nrows) break;                 // wave-uniform, monotone
            int r1 = p + 1;
            int x0 = S[n * XX + p / 3];  int t0 = p % 3;
            int x1 = S[n * XX + r1 / 3]; int t1 = r1 % 3;
            size_t b0 = ((size_t)(n * XX + x0) * TT + t0) * AA;
            size_t b1 = ((size_t)(n * XX + x1) * TT + t1) * AA;
            float pz0 = pred[b0 + KK + k], gx0 = gt[b0 + k];
            float pz1 = pred[b1 + KK + k], gx1 = gt[b1 + k];
            float ax0 = ax[x0], ax1 = ax[x1];
            float Z0 = pz0 * zs, Z1 = pz1 * zs;
            float sc0 = 1.0f - Z0 * inv_h, sc1 = 1.0f - Z1 * inv_h;
            float L0 = sc0 * (gx0 * xs + ax0);
            float L1 = sc1 * (gx1 * xs + ax1);
            float Y0 = sc0 * ayk;
            float l00 = gt[b0] * xstd0 + ax0;
            float l01 = gt[b1] * xstd0 + ax1;
            float width0 = fabsf(l01 - l00);

            float lm1 = __shfl_up(L0, 1);
            float ym1 = __shfl_up(Y0, 1);
            float y1v = __shfl(Y0, 1);
            float dYc, lc;
            if (lane == 0) {
                dYc = fabsf(y1v - Y0);
                lc = dYc;
            } else {
                dYc = fabsf(Y0 - ym1);
                float dx = L0 - lm1;
                lc = sqrtf(dx * dx + dYc * dYc);
            }
            float w = fabsf(L1 - L0) * dYc / (lc + EPSF);
            float wm1 = __shfl_up(w, 1);
            float werr = fabsf(w - (lane == 0 ? width0 : wm1));
            float dZ = fabsf(Z1 - Z0);
            if (lane < ncols) accp += werr + dZ;
        }
    }

    // ---- phase B: streaming (loss0 + loss1 + loss2) ----
    float a0 = 0.0f, a12 = 0.0f;
    {
        int sub = lane & 15;        // 16-B chunk within the 256-B field
        int rr = lane >> 4;         // row within group of 4
        int gw = blockIdx.x * 4 + wid;
        const int NW = NBLK * 4;
        const int NGROUP = NN * XX * TT / 4;   // 49152 = 8192 waves * 6

        #pragma unroll 2
        for (int g = gw; g < NGROUP; g += NW) {
            int row = 4 * g + rr;
            size_t base = (size_t)row * AA;
            float mi = mask[row];                       // L2-hot, 0.0 or 1.0
            float4a pv = ld4(pred + base + 2 * KK + sub * 4);
            float4a gv = ld4(gt   + base + 2 * KK + sub * 4);
            float pc = pred[base + 3 * KK];

            a0 += __logf(gv.x > 0.0f ? pv.x + EPSF : 1.0f - pv.x + EPSF)
                + __logf(gv.y > 0.0f ? pv.y + EPSF : 1.0f - pv.y + EPSF)
                + __logf(gv.z > 0.0f ? pv.z + EPSF : 1.0f - pv.z + EPSF)
                + __logf(gv.w > 0.0f ? pv.w + EPSF : 1.0f - pv.w + EPSF);

            if (sub == 0)
                a12 -= __logf(mi > 0.0f ? pc + EPSF : 1.0f - pc + EPSF);

            if (mi > 0.0f) {                            // exec-masked: no lines
                float4a pX = ld4(pred + base + sub * 4);
                float4a gX = ld4(gt   + base + sub * 4);
                a12 += gv.x * fabsf(pX.x - gX.x) + gv.y * fabsf(pX.y - gX.y)
                     + gv.z * fabsf(pX.z - gX.z) + gv.w * fabsf(pX.w - gX.w);
            }
        }
    }
    float local = 5.0f * accp + a12 - a0 * (1.0f / KK);

    // ---- phase C: reduce + last-block final ----
    __shared__ float red[256];
    red[tid] = local;
    __syncthreads();
    for (int s = 128; s > 0; s >>= 1) {
        if (tid < s) red[tid] += red[tid + s];
        __syncthreads();
    }

    __shared__ int s_last;
    if (tid == 0) {
        atomicAdd(&part[blockIdx.x & (NPART - 1)], (double)red[0]);
        __threadfence();
        int t = atomicAdd(ticket, 1);
        s_last = (t == NBLK - 1) ? 1 : 0;
    }
    __syncthreads();

    if (s_last) {
        __threadfence();
        double v = __hip_atomic_load(&part[tid], __ATOMIC_RELAXED,
                                     __HIP_MEMORY_SCOPE_AGENT);
        __shared__ double dred[256];
        dred[tid] = v;
        __syncthreads();
        for (int s = 128; s > 0; s >>= 1) {
            if (tid < s) dred[tid] += dred[tid + s];
            __syncthreads();
        }
        if (tid == 0) out[0] = (float)dred[0];
    }
}

extern "C" void kernel_launch(void* const* d_in, const int* in_sizes, int n_in,
                              void* d_out, int out_size, void* d_ws, size_t ws_size,
                              hipStream_t stream) {
    const float* pred = (const float*)d_in[0];
    const float* gt   = (const float*)d_in[1];
    const float* hcam = (const float*)d_in[2];
    const float* ax   = (const float*)d_in[3];
    const float* ay   = (const float*)d_in[4];
    const float* xstd = (const float*)d_in[5];
    const float* zstd = (const float*)d_in[6];
    float* out = (float*)d_out;

    char* ws = (char*)d_ws;
    double* part = (double*)ws;
    int* nsel   = (int*)(ws + 2048);
    int* ncols  = (int*)(ws + 3072);
    int* S      = (int*)(ws + 4096);
    int* Ck     = (int*)(ws + 266240);
    float* mask = (float*)(ws + 331776);
    int* ticket = (int*)(ws + 1118208);

    hipLaunchKernelGGL(k_meta, dim3(NN), dim3(256), 0, stream,
                       gt, nsel, ncols, S, Ck, part, mask, ticket);
    hipLaunchKernelGGL(k_fused, dim3(NBLK), dim3(256), 0, stream,
                       pred, gt, mask, hcam, ax, ay, xstd, zstd,
                       nsel, ncols, S, Ck, part, ticket, out);
}